// Round 2
// baseline (271.203 us; speedup 1.0000x reference)
//
#include <hip/hip_runtime.h>

__device__ __forceinline__ float4 exp4(float4 v) {
    float4 r;
    r.x = __expf(v.x); r.y = __expf(v.y); r.z = __expf(v.z); r.w = __expf(v.w);
    return r;
}

__device__ __forceinline__ void acc4(float4& a, float4 e) {
    a.x += e.x; a.y += e.y; a.z += e.z; a.w += e.w;
}

__device__ __forceinline__ float wave_reduce(float v) {
    #pragma unroll
    for (int off = 32; off > 0; off >>= 1) v += __shfl_down(v, off, 64);
    return v;
}

// process up to 4 rows (m >= 1), ids in r, loads issued together for ILP
__device__ __forceinline__ void procN(float4& acc, const float4* __restrict__ base,
                                      int4 r, int m) {
    float4 v0, v1, v2, v3;
    v0 = base[(size_t)r.x * 1024];
    if (m > 1) v1 = base[(size_t)r.y * 1024];
    if (m > 2) v2 = base[(size_t)r.z * 1024];
    if (m > 3) v3 = base[(size_t)r.w * 1024];
    acc4(acc, exp4(v0));
    if (m > 1) acc4(acc, exp4(v1));
    if (m > 2) acc4(acc, exp4(v2));
    if (m > 3) acc4(acc, exp4(v3));
}

// ================= PREP: build group->rows CSR once (counts pre-zeroed) ====================
// grid = 8, block = 1024
__global__ __launch_bounds__(1024) void PREP(const int* __restrict__ idx,
                                             int* __restrict__ counts,
                                             int* __restrict__ rowlist) {
    const int j = blockIdx.x * 1024 + threadIdx.x;   // 0..8191
    const int g = idx[j];
    const int p = atomicAdd(&counts[g], 1);
    if (p < 64) rowlist[(g << 6) + p] = j;
}

// ================= MEGA: blocks 0..255 theta1 path; blocks 256..4351 theta0 segment sums ====
// block = 256
__global__ __launch_bounds__(256) void MEGA(const float4* __restrict__ theta0,
                                            const float4* __restrict__ obs0,
                                            const int* __restrict__ idx,
                                            const float4* __restrict__ theta1,
                                            const float4* __restrict__ mapping1,
                                            float4* __restrict__ s0,   // nullptr => p2-atomics
                                            float* __restrict__ p2,
                                            float* __restrict__ lossA,
                                            float* __restrict__ m1,
                                            const int* __restrict__ counts,   // may be null
                                            const int* __restrict__ rowlist)  // may be null
{
    __shared__ int rows[64];
    __shared__ int cnt;
    __shared__ float wsum[4];
    __shared__ float p1s[16];

    const int t = threadIdx.x, lane = t & 63, wave = t >> 6;

    if (blockIdx.x < 256) {
        // ---- theta1: 16 row-sums of exp, then mapping1 slice -> m1 atomics ----
        const int b2 = blockIdx.x;
        #pragma unroll
        for (int rr = 0; rr < 4; ++rr) {
            const int lr = wave * 4 + rr;        // 0..15
            const float4* rp = theta1 + (size_t)(b2 * 16 + lr) * 512;
            float a = 0.f;
            #pragma unroll
            for (int i = 0; i < 8; ++i) {
                const float4 x = rp[lane + i * 64];
                a += __expf(x.x) + __expf(x.y) + __expf(x.z) + __expf(x.w);
            }
            a = wave_reduce(a);
            if (lane == 0) p1s[lr] = a;
        }
        __syncthreads();
        #pragma unroll
        for (int rr = 0; rr < 2; ++rr) {
            const int r = t * 2 + rr;            // 0..511
            const float4* mp = mapping1 + (size_t)r * 1024 + b2 * 4;
            float s = 0.f;
            #pragma unroll
            for (int j = 0; j < 4; ++j) {
                const float4 m = mp[j];
                s += m.x * p1s[j*4+0] + m.y * p1s[j*4+1]
                   + m.z * p1s[j*4+2] + m.w * p1s[j*4+3];
            }
            atomicAdd(&m1[r], s);
        }
        return;
    }

    // ---- theta0 segment-sum path ----
    const int bb    = blockIdx.x - 256;
    const int g     = bb & 1023;
    const int chunk = bb >> 10;
    const size_t o  = (size_t)g * 1024 + (size_t)chunk * 256 + t;
    const float4* base = theta0 + (size_t)chunk * 256 + t;

    // issue metadata + obs0 loads as early as possible
    int n = -1;
    int4 r0, r1, r2, r3;
    if (rowlist) {
        const int4* rl4 = (const int4*)(rowlist + (g << 6));
        r0 = rl4[0]; r1 = rl4[1]; r2 = rl4[2]; r3 = rl4[3];   // 64B prefetch, always in-bounds
        n = counts[g];
    }
    const float4 ob = obs0[o];

    float4 acc = {0.f, 0.f, 0.f, 0.f};
    if (n >= 0 && n <= 64) {
        if (n > 0) {
            procN(acc, base, r0, n);
            if (n > 4)  procN(acc, base, r1, n - 4);
            if (n > 8)  procN(acc, base, r2, n - 8);
            if (n > 12) procN(acc, base, r3, n - 12);
            if (n > 16) {
                const int* rl = rowlist + (g << 6);
                for (int s = 16; s < n; ++s)
                    acc4(acc, exp4(base[(size_t)rl[s] * 1024]));
            }
        }
    } else {
        // fallback: in-block scan (tiny ws, or CSR overflow n>64)
        if (t == 0) cnt = 0;
        __syncthreads();
        const int4* idx4 = (const int4*)idx;
        #pragma unroll
        for (int i = 0; i < 8; ++i) {
            const int j4 = t + i * 256;
            const int4 v = idx4[j4];
            if (v.x == g) { const int p = atomicAdd(&cnt, 1); if (p < 64) rows[p] = j4 * 4 + 0; }
            if (v.y == g) { const int p = atomicAdd(&cnt, 1); if (p < 64) rows[p] = j4 * 4 + 1; }
            if (v.z == g) { const int p = atomicAdd(&cnt, 1); if (p < 64) rows[p] = j4 * 4 + 2; }
            if (v.w == g) { const int p = atomicAdd(&cnt, 1); if (p < 64) rows[p] = j4 * 4 + 3; }
        }
        __syncthreads();
        const int nn = cnt;
        if (nn <= 64) {
            for (int s = 0; s < nn; ++s)
                acc4(acc, exp4(base[(size_t)rows[s] * 1024]));
        } else {
            for (int j = 0; j < 8192; ++j)
                if (idx[j] == g) acc4(acc, exp4(base[(size_t)j * 1024]));
        }
    }

    if (s0) {
        s0[o] = acc;
    } else {
        const int c = chunk * 1024 + t * 4;
        atomicAdd(&p2[c + 0], acc.x);
        atomicAdd(&p2[c + 1], acc.y);
        atomicAdd(&p2[c + 2], acc.z);
        atomicAdd(&p2[c + 3], acc.w);
    }

    const float dx = ob.x - acc.x, dy = ob.y - acc.y, dz = ob.z - acc.z, dw = ob.w - acc.w;
    float l = dx*dx + dy*dy + dz*dz + dw*dw;
    l = wave_reduce(l);
    if (lane == 0) wsum[wave] = l;
    __syncthreads();
    if (t == 0) atomicAdd(lossA, wsum[0] + wsum[1] + wsum[2] + wsum[3]);
}

// ================= K3F: column sums of s0 + loss_c; last block does loss_b + combine =========
// grid = 64, block = 1024
__global__ __launch_bounds__(1024) void K3F(const float* __restrict__ s0,
                                            const float* __restrict__ obs2,
                                            const float* __restrict__ lossA,
                                            float* __restrict__ lossC,
                                            int* __restrict__ ticket,
                                            const float* __restrict__ m1,
                                            const float* __restrict__ obs1,
                                            float* __restrict__ out) {
    __shared__ float part[16][64];
    __shared__ int isLast;
    const int tid = threadIdx.x, lane = tid & 63, wave = tid >> 6;
    const int col = blockIdx.x * 64 + lane;
    const float* p = s0 + (size_t)wave * 4096 + col;
    float a = 0.f;
    #pragma unroll 4
    for (int g = 0; g < 64; ++g) a += p[(size_t)g * 16 * 4096];
    part[wave][lane] = a;
    __syncthreads();
    if (wave == 0) {
        float s = 0.f;
        #pragma unroll
        for (int k = 0; k < 16; ++k) s += part[k][lane];
        const float d = obs2[col] - s;
        const float l = wave_reduce(d * d);
        if (lane == 0) {
            atomicAdd(lossC, l);
            __threadfence();
        }
    }
    __syncthreads();
    if (tid == 0) isLast = (atomicAdd(ticket, 1) == 63) ? 1 : 0;
    __syncthreads();
    if (!isLast) return;

    // ---- final: loss_b + combine ----
    __shared__ float wb[16];
    float lb = 0.f;
    if (tid < 512) { const float d = obs1[tid] - m1[tid]; lb = d * d; }
    lb = wave_reduce(lb);
    if (lane == 0) wb[wave] = lb;
    __syncthreads();
    if (tid == 0) {
        float sb = 0.f;
        #pragma unroll
        for (int i = 0; i < 16; ++i) sb += wb[i];
        const float sc = atomicAdd(lossC, 0.f);   // coherent L2 read
        const float la = lossA[0] / 4194304.f;
        const float lbf = sb / 512.f;
        const float lcf = 0.5f * sc / 4096.f;
        out[0] = (la + lbf + lcf) / 3.f;
    }
}

// ================= K4FB: fallback final (loss_b + loss_c from p2 + combine) =================
// grid = 1, block = 512
__global__ __launch_bounds__(512) void K4FB(const float* __restrict__ m1,
                                            const float* __restrict__ obs1,
                                            const float* __restrict__ losses,
                                            const float* __restrict__ p2,
                                            const float* __restrict__ obs2,
                                            float* __restrict__ out) {
    __shared__ float wb[8];
    __shared__ float wc[8];
    const int t = threadIdx.x, lane = t & 63, wave = t >> 6;
    const float d = obs1[t] - m1[t];
    const float lb = wave_reduce(d * d);
    float acc = 0.f;
    #pragma unroll
    for (int i = 0; i < 8; ++i) {
        const int c = t + i * 512;
        const float dd = obs2[c] - p2[c];
        acc += dd * dd;
    }
    const float lc = wave_reduce(acc);
    if (lane == 0) { wb[wave] = lb; wc[wave] = lc; }
    __syncthreads();
    if (t == 0) {
        float sb = 0.f, sc = 0.f;
        #pragma unroll
        for (int i = 0; i < 8; ++i) { sb += wb[i]; sc += wc[i]; }
        const float la = losses[0] / 4194304.f;
        out[0] = (la + sb / 512.f + 0.5f * sc / 4096.f) / 3.f;
    }
}

extern "C" void kernel_launch(void* const* d_in, const int* in_sizes, int n_in,
                              void* d_out, int out_size, void* d_ws, size_t ws_size,
                              hipStream_t stream) {
    const float* theta0   = (const float*)d_in[0];   // [8192,4096]
    const float* theta1   = (const float*)d_in[1];   // [4096,2048]
    const float* obs0     = (const float*)d_in[2];   // [1024,4096]
    const float* obs1     = (const float*)d_in[3];   // [512]
    const float* obs2     = (const float*)d_in[4];   // [4096]
    const int*   idx0     = (const int*)d_in[5];     // [8192]
    const float* mapping1 = (const float*)d_in[6];   // [512,4096]
    float* out = (float*)d_out;

    char* ws = (char*)d_ws;
    float* losses  = (float*)(ws + 0);       // [0]=lossA, [2]=lossC
    int*   ticket  = (int*)(ws + 12);
    float* m1      = (float*)(ws + 256);     // 512 floats
    float* p2      = (float*)(ws + 4096);    // 4096 floats (fallback only)
    int*   counts  = (int*)(ws + 20480);     // 1024 ints
    int*   rowlist = (int*)(ws + 24576);     // 1024*64 ints = 256 KB, ends 286720
    float* s0      = (float*)(ws + 524288);  // 16 MB

    const size_t NEED_CSR = 286720;
    const size_t NEED_S0  = 524288 + (size_t)1024 * 4096 * 4;
    const bool haveCSR = ws_size >= NEED_CSR;
    const bool path1   = ws_size >= NEED_S0;

    hipMemsetAsync(ws, 0, 24576, stream);  // losses + ticket + m1 + p2 + counts

    if (haveCSR) PREP<<<8, 1024, 0, stream>>>(idx0, counts, rowlist);

    MEGA<<<4352, 256, 0, stream>>>((const float4*)theta0, (const float4*)obs0, idx0,
                                   (const float4*)theta1, (const float4*)mapping1,
                                   path1 ? (float4*)s0 : nullptr, p2, &losses[0], m1,
                                   haveCSR ? counts : nullptr,
                                   haveCSR ? rowlist : nullptr);

    if (path1) {
        K3F<<<64, 1024, 0, stream>>>(s0, obs2, &losses[0], &losses[2], ticket,
                                     m1, obs1, out);
    } else {
        K4FB<<<1, 512, 0, stream>>>(m1, obs1, losses, p2, obs2, out);
    }
}

// Round 3
// 270.518 us; speedup vs baseline: 1.0025x; 1.0025x over previous
//
#include <hip/hip_runtime.h>

__device__ __forceinline__ float4 exp4(float4 v) {
    float4 r;
    r.x = __expf(v.x); r.y = __expf(v.y); r.z = __expf(v.z); r.w = __expf(v.w);
    return r;
}

__device__ __forceinline__ void acc4(float4& a, float4 e) {
    a.x += e.x; a.y += e.y; a.z += e.z; a.w += e.w;
}

__device__ __forceinline__ float wave_reduce(float v) {
    #pragma unroll
    for (int off = 32; off > 0; off >>= 1) v += __shfl_down(v, off, 64);
    return v;
}

// ================= PREP: zero p2part + build group->rows CSR (counts pre-zeroed) ============
// grid = 8, block = 1024
__global__ __launch_bounds__(1024) void PREP(const int* __restrict__ idx,
                                             int* __restrict__ counts,
                                             int* __restrict__ rowlist,
                                             float4* __restrict__ p2part4) {
    const int j = blockIdx.x * 1024 + threadIdx.x;   // 0..8191
    // zero the 64 x 4096 float partial buffers (65536 float4)
    const float4 z = {0.f, 0.f, 0.f, 0.f};
    #pragma unroll
    for (int i = 0; i < 8; ++i) p2part4[j + i * 8192] = z;
    const int g = idx[j];
    const int p = atomicAdd(&counts[g], 1);
    if (p < 64) rowlist[(g << 6) + p] = j;
}

// ================= MEGA: blocks 0..255 theta1 path; blocks 256..1279 theta0 groups ==========
// block = 256; each seg-block owns ONE group g and reads its rows as full 16 KB rows
__global__ __launch_bounds__(256) void MEGA(const float4* __restrict__ theta0,
                                            const float4* __restrict__ obs0,
                                            const int* __restrict__ idx,
                                            const float4* __restrict__ theta1,
                                            const float4* __restrict__ mapping1,
                                            float* __restrict__ p2part,   // [64][4096] or null
                                            float* __restrict__ p2direct, // fallback buffer
                                            float* __restrict__ lossA,
                                            float* __restrict__ m1part,   // [8][512]
                                            const int* __restrict__ counts,   // may be null
                                            const int* __restrict__ rowlist)  // may be null
{
    __shared__ int rows_lds[64];
    __shared__ int cnt;
    __shared__ float wsum[4];
    __shared__ float p1s[16];

    const int t = threadIdx.x, lane = t & 63, wave = t >> 6;

    if (blockIdx.x < 256) {
        // ---- theta1: 16 row-sums of exp, then mapping1 slice -> m1part atomics ----
        const int b2 = blockIdx.x;
        #pragma unroll
        for (int rr = 0; rr < 4; ++rr) {
            const int lr = wave * 4 + rr;        // 0..15
            const float4* rp = theta1 + (size_t)(b2 * 16 + lr) * 512;
            float a = 0.f;
            #pragma unroll
            for (int i = 0; i < 8; ++i) {
                const float4 x = rp[lane + i * 64];
                a += __expf(x.x) + __expf(x.y) + __expf(x.z) + __expf(x.w);
            }
            a = wave_reduce(a);
            if (lane == 0) p1s[lr] = a;
        }
        __syncthreads();
        float* mdst = m1part + (b2 & 7) * 512;
        #pragma unroll
        for (int rr = 0; rr < 2; ++rr) {
            const int r = t * 2 + rr;            // 0..511
            const float4* mp = mapping1 + (size_t)r * 1024 + b2 * 4;
            float s = 0.f;
            #pragma unroll
            for (int j = 0; j < 4; ++j) {
                const float4 m = mp[j];
                s += m.x * p1s[j*4+0] + m.y * p1s[j*4+1]
                   + m.z * p1s[j*4+2] + m.w * p1s[j*4+3];
            }
            atomicAdd(&mdst[r], s);
        }
        return;
    }

    // ---- theta0 segment path: one block per group, full rows ----
    const int g = blockIdx.x - 256;

    int n = -1;
    if (rowlist) n = counts[g];

    if (n >= 0 && n <= 64) {
        if (t < n) rows_lds[t] = rowlist[(g << 6) + t];
        __syncthreads();
    } else {
        // fallback: in-block scan of idx (tiny ws, or CSR overflow)
        if (t == 0) cnt = 0;
        __syncthreads();
        const int4* idx4 = (const int4*)idx;
        #pragma unroll
        for (int i = 0; i < 8; ++i) {
            const int j4 = t + i * 256;
            const int4 v = idx4[j4];
            if (v.x == g) { const int p = atomicAdd(&cnt, 1); if (p < 64) rows_lds[p] = j4 * 4 + 0; }
            if (v.y == g) { const int p = atomicAdd(&cnt, 1); if (p < 64) rows_lds[p] = j4 * 4 + 1; }
            if (v.z == g) { const int p = atomicAdd(&cnt, 1); if (p < 64) rows_lds[p] = j4 * 4 + 2; }
            if (v.w == g) { const int p = atomicAdd(&cnt, 1); if (p < 64) rows_lds[p] = j4 * 4 + 3; }
        }
        __syncthreads();
        n = cnt;
    }

    // obs0 row for this group (issued early, consumed at the end)
    const float4* ob4 = obs0 + (size_t)g * 1024;
    const float4 o0 = ob4[t], o1 = ob4[t + 256], o2 = ob4[t + 512], o3 = ob4[t + 768];

    float4 A0 = {0,0,0,0}, A1 = {0,0,0,0}, A2 = {0,0,0,0}, A3 = {0,0,0,0};

    if (n <= 64) {
        int s = 0;
        for (; s + 2 <= n; s += 2) {
            const float4* ra = theta0 + (size_t)rows_lds[s]     * 1024 + t;
            const float4* rb = theta0 + (size_t)rows_lds[s + 1] * 1024 + t;
            const float4 x0 = ra[0], x1 = ra[256], x2 = ra[512], x3 = ra[768];
            const float4 y0 = rb[0], y1 = rb[256], y2 = rb[512], y3 = rb[768];
            acc4(A0, exp4(x0)); acc4(A1, exp4(x1)); acc4(A2, exp4(x2)); acc4(A3, exp4(x3));
            acc4(A0, exp4(y0)); acc4(A1, exp4(y1)); acc4(A2, exp4(y2)); acc4(A3, exp4(y3));
        }
        if (s < n) {
            const float4* ra = theta0 + (size_t)rows_lds[s] * 1024 + t;
            const float4 x0 = ra[0], x1 = ra[256], x2 = ra[512], x3 = ra[768];
            acc4(A0, exp4(x0)); acc4(A1, exp4(x1)); acc4(A2, exp4(x2)); acc4(A3, exp4(x3));
        }
    } else {
        // pathological overflow (never for this data) — slow but correct
        for (int j = 0; j < 8192; ++j) {
            if (idx[j] == g) {
                const float4* ra = theta0 + (size_t)j * 1024 + t;
                const float4 x0 = ra[0], x1 = ra[256], x2 = ra[512], x3 = ra[768];
                acc4(A0, exp4(x0)); acc4(A1, exp4(x1)); acc4(A2, exp4(x2)); acc4(A3, exp4(x3));
            }
        }
    }

    // column-sum partials (hierarchical: 16 groups share each of 64 buffers)
    float* dst = p2part ? (p2part + (size_t)(g & 63) * 4096) : p2direct;
    atomicAdd(&dst[4*t + 0], A0.x); atomicAdd(&dst[4*t + 1], A0.y);
    atomicAdd(&dst[4*t + 2], A0.z); atomicAdd(&dst[4*t + 3], A0.w);
    atomicAdd(&dst[4*(t+256) + 0], A1.x); atomicAdd(&dst[4*(t+256) + 1], A1.y);
    atomicAdd(&dst[4*(t+256) + 2], A1.z); atomicAdd(&dst[4*(t+256) + 3], A1.w);
    atomicAdd(&dst[4*(t+512) + 0], A2.x); atomicAdd(&dst[4*(t+512) + 1], A2.y);
    atomicAdd(&dst[4*(t+512) + 2], A2.z); atomicAdd(&dst[4*(t+512) + 3], A2.w);
    atomicAdd(&dst[4*(t+768) + 0], A3.x); atomicAdd(&dst[4*(t+768) + 1], A3.y);
    atomicAdd(&dst[4*(t+768) + 2], A3.z); atomicAdd(&dst[4*(t+768) + 3], A3.w);

    // loss_a for this group-row
    const float d00 = o0.x - A0.x, d01 = o0.y - A0.y, d02 = o0.z - A0.z, d03 = o0.w - A0.w;
    const float d10 = o1.x - A1.x, d11 = o1.y - A1.y, d12 = o1.z - A1.z, d13 = o1.w - A1.w;
    const float d20 = o2.x - A2.x, d21 = o2.y - A2.y, d22 = o2.z - A2.z, d23 = o2.w - A2.w;
    const float d30 = o3.x - A3.x, d31 = o3.y - A3.y, d32 = o3.z - A3.z, d33 = o3.w - A3.w;
    float l = d00*d00 + d01*d01 + d02*d02 + d03*d03
            + d10*d10 + d11*d11 + d12*d12 + d13*d13
            + d20*d20 + d21*d21 + d22*d22 + d23*d23
            + d30*d30 + d31*d31 + d32*d32 + d33*d33;
    l = wave_reduce(l);
    if (lane == 0) wsum[wave] = l;
    __syncthreads();
    if (t == 0) atomicAdd(lossA, wsum[0] + wsum[1] + wsum[2] + wsum[3]);
}

// ================= FIN: reduce p2part -> loss_c; last block: loss_b + combine ===============
// grid = 64, block = 256
__global__ __launch_bounds__(256) void FIN(const float* __restrict__ p2part,
                                           const float* __restrict__ obs2,
                                           const float* __restrict__ lossA,
                                           float* __restrict__ lossC,
                                           int* __restrict__ ticket,
                                           const float* __restrict__ m1part,
                                           const float* __restrict__ obs1,
                                           float* __restrict__ out) {
    __shared__ float part[4][64];
    __shared__ float wb[4];
    __shared__ int isLast;
    const int t = threadIdx.x, lane = t & 63, wave = t >> 6;
    const int col = blockIdx.x * 64 + lane;
    const float* p = p2part + (size_t)(wave * 16) * 4096 + col;
    float a = 0.f;
    #pragma unroll
    for (int k = 0; k < 16; ++k) a += p[(size_t)k * 4096];
    part[wave][lane] = a;
    __syncthreads();
    if (wave == 0) {
        const float s = part[0][lane] + part[1][lane] + part[2][lane] + part[3][lane];
        const float d = obs2[col] - s;
        const float l = wave_reduce(d * d);
        if (lane == 0) {
            atomicAdd(lossC, l);
            __threadfence();
        }
    }
    __syncthreads();
    if (t == 0) isLast = (atomicAdd(ticket, 1) == 63) ? 1 : 0;
    __syncthreads();
    if (!isLast) return;

    // ---- final: loss_b + combine ----
    float lb = 0.f;
    #pragma unroll
    for (int rr = 0; rr < 2; ++rr) {
        const int r = t * 2 + rr;            // 0..511
        float m = 0.f;
        #pragma unroll
        for (int k = 0; k < 8; ++k) m += m1part[k * 512 + r];
        const float d = obs1[r] - m;
        lb += d * d;
    }
    lb = wave_reduce(lb);
    if (lane == 0) wb[wave] = lb;
    __syncthreads();
    if (t == 0) {
        const float sb = wb[0] + wb[1] + wb[2] + wb[3];
        const float sc = atomicAdd(lossC, 0.f);   // coherent read
        const float la = lossA[0] / 4194304.f;
        out[0] = (la + sb / 512.f + 0.5f * sc / 4096.f) / 3.f;
    }
}

// ================= FINFB: fallback final (loss_b + loss_c from p2direct + combine) ==========
// grid = 1, block = 512
__global__ __launch_bounds__(512) void FINFB(const float* __restrict__ m1part,
                                             const float* __restrict__ obs1,
                                             const float* __restrict__ losses,
                                             const float* __restrict__ p2,
                                             const float* __restrict__ obs2,
                                             float* __restrict__ out) {
    __shared__ float wb[8];
    __shared__ float wc[8];
    const int t = threadIdx.x, lane = t & 63, wave = t >> 6;
    float m = 0.f;
    #pragma unroll
    for (int k = 0; k < 8; ++k) m += m1part[k * 512 + t];
    const float d = obs1[t] - m;
    const float lb = wave_reduce(d * d);
    float acc = 0.f;
    #pragma unroll
    for (int i = 0; i < 8; ++i) {
        const int c = t + i * 512;
        const float dd = obs2[c] - p2[c];
        acc += dd * dd;
    }
    const float lc = wave_reduce(acc);
    if (lane == 0) { wb[wave] = lb; wc[wave] = lc; }
    __syncthreads();
    if (t == 0) {
        float sb = 0.f, sc = 0.f;
        #pragma unroll
        for (int i = 0; i < 8; ++i) { sb += wb[i]; sc += wc[i]; }
        const float la = losses[0] / 4194304.f;
        out[0] = (la + sb / 512.f + 0.5f * sc / 4096.f) / 3.f;
    }
}

extern "C" void kernel_launch(void* const* d_in, const int* in_sizes, int n_in,
                              void* d_out, int out_size, void* d_ws, size_t ws_size,
                              hipStream_t stream) {
    const float* theta0   = (const float*)d_in[0];   // [8192,4096]
    const float* theta1   = (const float*)d_in[1];   // [4096,2048]
    const float* obs0     = (const float*)d_in[2];   // [1024,4096]
    const float* obs1     = (const float*)d_in[3];   // [512]
    const float* obs2     = (const float*)d_in[4];   // [4096]
    const int*   idx0     = (const int*)d_in[5];     // [8192]
    const float* mapping1 = (const float*)d_in[6];   // [512,4096]
    float* out = (float*)d_out;

    char* ws = (char*)d_ws;
    float* losses  = (float*)(ws + 0);        // [0]=lossA, [2]=lossC
    int*   ticket  = (int*)(ws + 16);
    float* m1part  = (float*)(ws + 1024);     // 8*512 floats, ends 17408
    int*   counts  = (int*)(ws + 17408);      // 1024 ints, ends 21504 (main)
    float* p2fb    = (float*)(ws + 21504);    // 4096 floats, ends 37888 (fallback)
    int*   rowlist = (int*)(ws + 65536);      // 1024*64 ints, ends 327680
    float* p2part  = (float*)(ws + 327680);   // 64*4096 floats, ends 1376256

    const size_t NEED = 1376256;
    const bool haveWS = ws_size >= NEED;

    hipMemsetAsync(ws, 0, 37888, stream);  // losses + ticket + m1part + counts + p2fb

    if (haveWS) {
        PREP<<<8, 1024, 0, stream>>>(idx0, counts, rowlist, (float4*)p2part);
        MEGA<<<1280, 256, 0, stream>>>((const float4*)theta0, (const float4*)obs0, idx0,
                                       (const float4*)theta1, (const float4*)mapping1,
                                       p2part, nullptr, &losses[0], m1part,
                                       counts, rowlist);
        FIN<<<64, 256, 0, stream>>>(p2part, obs2, &losses[0], &losses[2], ticket,
                                    m1part, obs1, out);
    } else {
        MEGA<<<1280, 256, 0, stream>>>((const float4*)theta0, (const float4*)obs0, idx0,
                                       (const float4*)theta1, (const float4*)mapping1,
                                       nullptr, p2fb, &losses[0], m1part,
                                       nullptr, nullptr);
        FINFB<<<1, 512, 0, stream>>>(m1part, obs1, losses, p2fb, obs2, out);
    }
}

// Round 4
// 269.839 us; speedup vs baseline: 1.0051x; 1.0025x over previous
//
#include <hip/hip_runtime.h>

typedef float vf4 __attribute__((ext_vector_type(4)));

__device__ __forceinline__ float4 ntload4(const float4* p) {
    vf4 v = __builtin_nontemporal_load((const vf4*)p);
    float4 r; r.x = v.x; r.y = v.y; r.z = v.z; r.w = v.w;
    return r;
}

__device__ __forceinline__ float4 exp4(float4 v) {
    float4 r;
    r.x = __expf(v.x); r.y = __expf(v.y); r.z = __expf(v.z); r.w = __expf(v.w);
    return r;
}

__device__ __forceinline__ void acc4(float4& a, float4 e) {
    a.x += e.x; a.y += e.y; a.z += e.z; a.w += e.w;
}

__device__ __forceinline__ float wave_reduce(float v) {
    #pragma unroll
    for (int off = 32; off > 0; off >>= 1) v += __shfl_down(v, off, 64);
    return v;
}

// ================= PREP: build group->rows CSR (counts pre-zeroed by memset) ================
// grid = 8, block = 1024
__global__ __launch_bounds__(1024) void PREP(const int* __restrict__ idx,
                                             int* __restrict__ counts,
                                             int* __restrict__ rowlist) {
    const int j = blockIdx.x * 1024 + threadIdx.x;   // 0..8191
    const int g = idx[j];
    const int p = atomicAdd(&counts[g], 1);
    if (p < 64) rowlist[(g << 6) + p] = j;
}

// ================= MEGA: blocks 0..255 theta1 path; blocks 256..4351 theta0 (g,chunk) ======
// block = 256
__global__ __launch_bounds__(256) void MEGA(const float4* __restrict__ theta0,
                                            const float4* __restrict__ obs0,
                                            const int* __restrict__ idx,
                                            const float4* __restrict__ theta1,
                                            const float4* __restrict__ mapping1,
                                            float4* __restrict__ s0,     // nullptr => p2fb atomics
                                            float* __restrict__ p2fb,
                                            float* __restrict__ lossA,
                                            float* __restrict__ m1part,  // [8][512]
                                            const int* __restrict__ counts,   // may be null
                                            const int* __restrict__ rowlist)  // may be null
{
    __shared__ int rows_lds[64];
    __shared__ int cnt;
    __shared__ float wsum[4];
    __shared__ float p1s[16];

    const int t = threadIdx.x, lane = t & 63, wave = t >> 6;

    if (blockIdx.x < 256) {
        // ---- theta1: 16 row-sums of exp (nt loads), then mapping1 slice -> m1part ----
        const int b2 = blockIdx.x;
        #pragma unroll
        for (int rr = 0; rr < 4; ++rr) {
            const int lr = wave * 4 + rr;        // 0..15
            const float4* rp = theta1 + (size_t)(b2 * 16 + lr) * 512;
            float a = 0.f;
            #pragma unroll
            for (int i = 0; i < 8; ++i) {
                const float4 x = ntload4(rp + lane + i * 64);
                a += __expf(x.x) + __expf(x.y) + __expf(x.z) + __expf(x.w);
            }
            a = wave_reduce(a);
            if (lane == 0) p1s[lr] = a;
        }
        __syncthreads();
        float* mdst = m1part + (b2 & 7) * 512;
        #pragma unroll
        for (int rr = 0; rr < 2; ++rr) {
            const int r = t * 2 + rr;            // 0..511
            const float4* mp = mapping1 + (size_t)r * 1024 + b2 * 4;
            float s = 0.f;
            #pragma unroll
            for (int j = 0; j < 4; ++j) {
                const float4 m = mp[j];
                s += m.x * p1s[j*4+0] + m.y * p1s[j*4+1]
                   + m.z * p1s[j*4+2] + m.w * p1s[j*4+3];
            }
            atomicAdd(&mdst[r], s);
        }
        return;
    }

    // ---- theta0 segment path: block (g, chunk) ----
    const int bb = blockIdx.x - 256;
    const int g  = bb & 1023;
    const int c  = bb >> 10;

    int n;
    if (counts) {
        n = counts[g];
        if (t < 64) rows_lds[t] = rowlist[(g << 6) + t];
        __syncthreads();
    } else {
        // in-block scan fallback
        if (t == 0) cnt = 0;
        __syncthreads();
        const int4* idx4 = (const int4*)idx;
        #pragma unroll
        for (int i = 0; i < 8; ++i) {
            const int j4 = t + i * 256;
            const int4 v = idx4[j4];
            if (v.x == g) { const int p = atomicAdd(&cnt, 1); if (p < 64) rows_lds[p] = j4 * 4 + 0; }
            if (v.y == g) { const int p = atomicAdd(&cnt, 1); if (p < 64) rows_lds[p] = j4 * 4 + 1; }
            if (v.z == g) { const int p = atomicAdd(&cnt, 1); if (p < 64) rows_lds[p] = j4 * 4 + 2; }
            if (v.w == g) { const int p = atomicAdd(&cnt, 1); if (p < 64) rows_lds[p] = j4 * 4 + 3; }
        }
        __syncthreads();
        n = cnt;
    }

    const float4* base = theta0 + (size_t)c * 256 + t;
    float4 acc0 = {0,0,0,0}, acc1 = {0,0,0,0};

    if (n <= 64) {
        // 8-deep pipelined gather: two 4-row banks, all branches wave-uniform, static regs
        float4 A0, A1, A2, A3, B0, B1, B2, B3;
        if (n > 0)  A0 = ntload4(base + (size_t)rows_lds[0]  * 1024);
        if (n > 1)  A1 = ntload4(base + (size_t)rows_lds[1]  * 1024);
        if (n > 2)  A2 = ntload4(base + (size_t)rows_lds[2]  * 1024);
        if (n > 3)  A3 = ntload4(base + (size_t)rows_lds[3]  * 1024);
        if (n > 4)  B0 = ntload4(base + (size_t)rows_lds[4]  * 1024);
        if (n > 5)  B1 = ntload4(base + (size_t)rows_lds[5]  * 1024);
        if (n > 6)  B2 = ntload4(base + (size_t)rows_lds[6]  * 1024);
        if (n > 7)  B3 = ntload4(base + (size_t)rows_lds[7]  * 1024);

        if (n > 0)  acc4(acc0, exp4(A0));
        if (n > 1)  acc4(acc1, exp4(A1));
        if (n > 2)  acc4(acc0, exp4(A2));
        if (n > 3)  acc4(acc1, exp4(A3));
        if (n > 8)  A0 = ntload4(base + (size_t)rows_lds[8]  * 1024);
        if (n > 9)  A1 = ntload4(base + (size_t)rows_lds[9]  * 1024);
        if (n > 10) A2 = ntload4(base + (size_t)rows_lds[10] * 1024);
        if (n > 11) A3 = ntload4(base + (size_t)rows_lds[11] * 1024);

        if (n > 4)  acc4(acc0, exp4(B0));
        if (n > 5)  acc4(acc1, exp4(B1));
        if (n > 6)  acc4(acc0, exp4(B2));
        if (n > 7)  acc4(acc1, exp4(B3));
        if (n > 12) B0 = ntload4(base + (size_t)rows_lds[12] * 1024);
        if (n > 13) B1 = ntload4(base + (size_t)rows_lds[13] * 1024);
        if (n > 14) B2 = ntload4(base + (size_t)rows_lds[14] * 1024);
        if (n > 15) B3 = ntload4(base + (size_t)rows_lds[15] * 1024);

        if (n > 8)  acc4(acc0, exp4(A0));
        if (n > 9)  acc4(acc1, exp4(A1));
        if (n > 10) acc4(acc0, exp4(A2));
        if (n > 11) acc4(acc1, exp4(A3));
        if (n > 12) acc4(acc0, exp4(B0));
        if (n > 13) acc4(acc1, exp4(B1));
        if (n > 14) acc4(acc0, exp4(B2));
        if (n > 15) acc4(acc1, exp4(B3));

        // rare tail (n > 16)
        for (int s = 16; s < n; ++s)
            acc4(acc0, exp4(ntload4(base + (size_t)rows_lds[s] * 1024)));
    } else {
        // pathological overflow — slow but correct
        for (int j = 0; j < 8192; ++j)
            if (idx[j] == g) acc4(acc0, exp4(ntload4(base + (size_t)j * 1024)));
    }

    float4 sv;
    sv.x = acc0.x + acc1.x; sv.y = acc0.y + acc1.y;
    sv.z = acc0.z + acc1.z; sv.w = acc0.w + acc1.w;

    const size_t o = (size_t)g * 1024 + (size_t)c * 256 + t;
    if (s0) {
        s0[o] = sv;
    } else {
        const int cc = c * 1024 + t * 4;
        atomicAdd(&p2fb[cc + 0], sv.x);
        atomicAdd(&p2fb[cc + 1], sv.y);
        atomicAdd(&p2fb[cc + 2], sv.z);
        atomicAdd(&p2fb[cc + 3], sv.w);
    }

    const float4 ob = obs0[o];
    const float dx = ob.x - sv.x, dy = ob.y - sv.y, dz = ob.z - sv.z, dw = ob.w - sv.w;
    float l = dx*dx + dy*dy + dz*dz + dw*dw;
    l = wave_reduce(l);
    if (lane == 0) wsum[wave] = l;
    __syncthreads();
    if (t == 0) atomicAdd(lossA, wsum[0] + wsum[1] + wsum[2] + wsum[3]);
}

// ================= K3F: column sums of s0 + loss_c; last block does loss_b + combine =========
// grid = 64, block = 1024
__global__ __launch_bounds__(1024) void K3F(const float* __restrict__ s0,
                                            const float* __restrict__ obs2,
                                            const float* __restrict__ lossA,
                                            float* __restrict__ lossC,
                                            int* __restrict__ ticket,
                                            const float* __restrict__ m1part,
                                            const float* __restrict__ obs1,
                                            float* __restrict__ out) {
    __shared__ float part[16][64];
    __shared__ int isLast;
    const int tid = threadIdx.x, lane = tid & 63, wave = tid >> 6;
    const int col = blockIdx.x * 64 + lane;
    const float* p = s0 + (size_t)wave * 4096 + col;
    float a = 0.f;
    #pragma unroll 4
    for (int g = 0; g < 64; ++g) a += p[(size_t)g * 16 * 4096];
    part[wave][lane] = a;
    __syncthreads();
    if (wave == 0) {
        float s = 0.f;
        #pragma unroll
        for (int k = 0; k < 16; ++k) s += part[k][lane];
        const float d = obs2[col] - s;
        const float l = wave_reduce(d * d);
        if (lane == 0) {
            atomicAdd(lossC, l);
            __threadfence();
        }
    }
    __syncthreads();
    if (tid == 0) isLast = (atomicAdd(ticket, 1) == 63) ? 1 : 0;
    __syncthreads();
    if (!isLast) return;

    // ---- final: loss_b + combine ----
    __shared__ float wb[16];
    float lb = 0.f;
    if (tid < 512) {
        float m = 0.f;
        #pragma unroll
        for (int k = 0; k < 8; ++k) m += m1part[k * 512 + tid];
        const float d = obs1[tid] - m;
        lb = d * d;
    }
    lb = wave_reduce(lb);
    if (lane == 0) wb[wave] = lb;
    __syncthreads();
    if (tid == 0) {
        float sb = 0.f;
        #pragma unroll
        for (int i = 0; i < 16; ++i) sb += wb[i];
        const float sc = atomicAdd(lossC, 0.f);   // coherent read
        const float la = lossA[0] / 4194304.f;
        out[0] = (la + sb / 512.f + 0.5f * sc / 4096.f) / 3.f;
    }
}

// ================= FINFB: fallback final (loss_b + loss_c from p2fb + combine) ==============
// grid = 1, block = 512
__global__ __launch_bounds__(512) void FINFB(const float* __restrict__ m1part,
                                             const float* __restrict__ obs1,
                                             const float* __restrict__ losses,
                                             const float* __restrict__ p2,
                                             const float* __restrict__ obs2,
                                             float* __restrict__ out) {
    __shared__ float wb[8];
    __shared__ float wc[8];
    const int t = threadIdx.x, lane = t & 63, wave = t >> 6;
    float m = 0.f;
    #pragma unroll
    for (int k = 0; k < 8; ++k) m += m1part[k * 512 + t];
    const float d = obs1[t] - m;
    const float lb = wave_reduce(d * d);
    float acc = 0.f;
    #pragma unroll
    for (int i = 0; i < 8; ++i) {
        const int c = t + i * 512;
        const float dd = obs2[c] - p2[c];
        acc += dd * dd;
    }
    const float lc = wave_reduce(acc);
    if (lane == 0) { wb[wave] = lb; wc[wave] = lc; }
    __syncthreads();
    if (t == 0) {
        float sb = 0.f, sc = 0.f;
        #pragma unroll
        for (int i = 0; i < 8; ++i) { sb += wb[i]; sc += wc[i]; }
        const float la = losses[0] / 4194304.f;
        out[0] = (la + sb / 512.f + 0.5f * sc / 4096.f) / 3.f;
    }
}

extern "C" void kernel_launch(void* const* d_in, const int* in_sizes, int n_in,
                              void* d_out, int out_size, void* d_ws, size_t ws_size,
                              hipStream_t stream) {
    const float* theta0   = (const float*)d_in[0];   // [8192,4096]
    const float* theta1   = (const float*)d_in[1];   // [4096,2048]
    const float* obs0     = (const float*)d_in[2];   // [1024,4096]
    const float* obs1     = (const float*)d_in[3];   // [512]
    const float* obs2     = (const float*)d_in[4];   // [4096]
    const int*   idx0     = (const int*)d_in[5];     // [8192]
    const float* mapping1 = (const float*)d_in[6];   // [512,4096]
    float* out = (float*)d_out;

    char* ws = (char*)d_ws;
    float* losses  = (float*)(ws + 0);         // [0]=lossA, [2]=lossC
    int*   ticket  = (int*)(ws + 16);
    float* m1part  = (float*)(ws + 64);        // 8*512 floats, ends 16448
    int*   counts  = (int*)(ws + 16640);       // 1024 ints, ends 20736
    float* p2fb    = (float*)(ws + 20736);     // 4096 floats, ends 37120
    float* s0      = (float*)(ws + 65536);     // 16 MB, ends 16842752
    int*   rowlist = (int*)(ws + 16842752);    // 1024*64 ints, ends 17104896

    const size_t NEED_S0  = 16842752;
    const size_t NEED_ALL = 17104896;
    const bool haveS0  = ws_size >= NEED_S0;
    const bool haveCSR = ws_size >= NEED_ALL;

    hipMemsetAsync(ws, 0, 37120, stream);  // losses + ticket + m1part + counts + p2fb

    if (haveCSR) PREP<<<8, 1024, 0, stream>>>(idx0, counts, rowlist);

    MEGA<<<4352, 256, 0, stream>>>((const float4*)theta0, (const float4*)obs0, idx0,
                                   (const float4*)theta1, (const float4*)mapping1,
                                   haveS0 ? (float4*)s0 : nullptr, p2fb,
                                   &losses[0], m1part,
                                   haveCSR ? counts : nullptr,
                                   haveCSR ? rowlist : nullptr);

    if (haveS0) {
        K3F<<<64, 1024, 0, stream>>>(s0, obs2, &losses[0], &losses[2], ticket,
                                     m1part, obs1, out);
    } else {
        FINFB<<<1, 512, 0, stream>>>(m1part, obs1, losses, p2fb, obs2, out);
    }
}